// Round 14
// baseline (150.843 us; speedup 1.0000x reference)
//
#include <hip/hip_runtime.h>

#define DD 128

constexpr int cN0 = 100000, cN1 = 50000, cN2 = 10000;
constexpr int NB1c = (cN1 + 31) / 32;   // 1563 buckets of 32 dsts (graph 1)
constexpr int NB2c = (cN2 + 15) / 16;   // 625 buckets of 16 dsts (graph 2)
constexpr int CAP1H = 1024;             // half-bucket: mean 512, +22 sigma
constexpr int CAP2 = 1024;              // mean 512,  sigma 23 -> safe

typedef unsigned long long ull;

// ---------------------------------------------------------------------------
// bf16 helpers (packed 2x bf16 in u32; lo 16 = even col, hi 16 = odd col)
// ---------------------------------------------------------------------------
__device__ __forceinline__ float bf_lo(unsigned int u) {
  return __uint_as_float(u << 16);
}
__device__ __forceinline__ float bf_hi(unsigned int u) {
  return __uint_as_float(u & 0xFFFF0000u);
}
__device__ __forceinline__ unsigned int pack_bf2(float a, float b) {
  unsigned int ua = __float_as_uint(a), ub = __float_as_uint(b);
  ua += 0x7FFFu + ((ua >> 16) & 1u);   // round-to-nearest-even
  ub += 0x7FFFu + ((ub >> 16) & 1u);
  return (ua >> 16) | (ub & 0xFFFF0000u);
}

// payload: hi32 = weight bits, lo32 = (src << 5) | dlow5
#define PAY_GATHER(PK, VX, VY)                                       \
  {                                                                  \
    int s_ = ((int)(unsigned int)(PK)) >> 5;                         \
    unsigned int v_ = h_in[(size_t)s_ * 64 + lane];                  \
    float w_ = __uint_as_float((unsigned int)((PK) >> 32));          \
    VX += bf_lo(v_) * w_;                                            \
    VY += bf_hi(v_) * w_;                                            \
  }

// ---------------------------------------------------------------------------
// One-wave exclusive scan of raw[0..nb) into lds_out (nb <= 192).
// Caller must __syncthreads() after.
// ---------------------------------------------------------------------------
__device__ __forceinline__ void wave_scan_bsum(
    const int* __restrict__ raw, int nb, int* lds_out, int tid) {
  if (tid < 64) {
    int carry = 0;
    for (int base = 0; base < nb; base += 64) {
      int i = base + tid;
      int orig = (i < nb) ? raw[i] : 0;
      int v = orig;
      for (int d = 1; d < 64; d <<= 1) {
        int u = __shfl_up(v, d);
        if (tid >= d) v += u;
      }
      if (i < nb) lds_out[i] = carry + v - orig;
      carry += __shfl(v, 63);
    }
  }
}

// ---------------------------------------------------------------------------
// Prep kernel (one launch): blocks [0, nA) run pass A (coarse histogram),
// blocks [nA, nA+ncvt) convert x -> bf16, last 16 blocks transpose W.
// ---------------------------------------------------------------------------
__global__ __launch_bounds__(1024) void prep_kernel(
    const int* __restrict__ d1, int E1, int nA1, int* __restrict__ bh1,
    const int* __restrict__ d2, int E2, int nA2, int* __restrict__ bh2,
    const float* __restrict__ x, unsigned int* __restrict__ xb, long long n8,
    int ncvt, const float* __restrict__ W, float* __restrict__ WT) {
  __shared__ int hist[NB1c];
  int blk = blockIdx.x;
  int t = threadIdx.x;
  int nA = nA1 + nA2;

  if (blk < nA) {
    const int* dst; int E, NB, nblk, sh; int* bh; int lb;
    if (blk < nA1) { dst = d1; E = E1; NB = NB1c; nblk = nA1; bh = bh1; sh = 5; lb = blk; }
    else { dst = d2; E = E2; NB = NB2c; nblk = nA2; bh = bh2; sh = 4; lb = blk - nA1; }

    for (int i = t; i < NB; i += 1024) hist[i] = 0;
    __syncthreads();

    int eb = lb * 4096;
#pragma unroll
    for (int r = 0; r < 4; ++r) {
      int e = eb + r * 1024 + t;
      if (e < E) atomicAdd(&hist[dst[e] >> sh], 1);
    }
    __syncthreads();
    for (int i = t; i < NB; i += 1024) bh[(size_t)i * nblk + lb] = hist[i];
  } else if (blk < nA + ncvt) {
    long long i = (long long)(blk - nA) * 1024 + t;
    if (i < n8) {
      const float4* f4 = reinterpret_cast<const float4*>(x) + i * 2;
      float4 a = f4[0];
      float4 b = f4[1];
      uint4 o;
      o.x = pack_bf2(a.x, a.y);
      o.y = pack_bf2(a.z, a.w);
      o.z = pack_bf2(b.x, b.y);
      o.w = pack_bf2(b.z, b.w);
      reinterpret_cast<uint4*>(xb)[i] = o;
    }
  } else {
    int idx = (blk - nA - ncvt) * 1024 + t;
    if (idx < DD * DD) {
      int c = idx >> 7;
      int d = idx & 127;
      WT[d * DD + c] = W[idx];
    }
  }
}

// ---------------------------------------------------------------------------
// Scan stage 1: per-4096-chunk exclusive scan (256 thr x 16 via int4).
// S stays CHUNK-LOCAL; bsum holds RAW chunk totals (consumers scan them).
// ---------------------------------------------------------------------------
__global__ __launch_bounds__(256) void scan_blk2_kernel(
    const int* __restrict__ cnt1, int n1, int* __restrict__ ofs1, int* __restrict__ bsum1, int nb1,
    const int* __restrict__ cnt2, int n2, int* __restrict__ ofs2, int* __restrict__ bsum2) {
  const int* cnt; int n; int* ofs; int* bsum; int lb;
  if ((int)blockIdx.x < nb1) { cnt = cnt1; n = n1; ofs = ofs1; bsum = bsum1; lb = blockIdx.x; }
  else                       { cnt = cnt2; n = n2; ofs = ofs2; bsum = bsum2; lb = blockIdx.x - nb1; }

  __shared__ int tsum[256];
  int t = threadIdx.x;
  int base = lb * 4096 + t * 16;
  bool in = (base + 16 <= n);

  int v[16];
  if (in) {
    const int4* p4 = reinterpret_cast<const int4*>(cnt + base);
    int4 a = p4[0], b = p4[1], c = p4[2], d = p4[3];
    v[0]=a.x; v[1]=a.y; v[2]=a.z; v[3]=a.w;
    v[4]=b.x; v[5]=b.y; v[6]=b.z; v[7]=b.w;
    v[8]=c.x; v[9]=c.y; v[10]=c.z; v[11]=c.w;
    v[12]=d.x; v[13]=d.y; v[14]=d.z; v[15]=d.w;
  } else {
#pragma unroll
    for (int k = 0; k < 16; ++k) v[k] = 0;
  }
#pragma unroll
  for (int k = 1; k < 16; ++k) v[k] += v[k - 1];

  tsum[t] = v[15];
  __syncthreads();
  for (int d_ = 1; d_ < 256; d_ <<= 1) {
    int x = (t >= d_) ? tsum[t - d_] : 0;
    __syncthreads();
    tsum[t] += x;
    __syncthreads();
  }
  int ex = (t == 0) ? 0 : tsum[t - 1];

  if (in) {
    int4* q = reinterpret_cast<int4*>(ofs + base);
    q[0] = make_int4(ex,         ex + v[0],  ex + v[1],  ex + v[2]);
    q[1] = make_int4(ex + v[3],  ex + v[4],  ex + v[5],  ex + v[6]);
    q[2] = make_int4(ex + v[7],  ex + v[8],  ex + v[9],  ex + v[10]);
    q[3] = make_int4(ex + v[11], ex + v[12], ex + v[13], ex + v[14]);
  }
  if (t == 255) bsum[lb] = tsum[255];
}

// ---------------------------------------------------------------------------
// Pass B (LDS-binned, wave-coalesced scatter). Hierarchical wave-shuffle
// scan (2 barriers) replaces the 1024-wide Hillis-Steele (20 barriers).
// ---------------------------------------------------------------------------
__global__ __launch_bounds__(1024) void passB_kernel(
    const int* __restrict__ d1, const int* __restrict__ s1, const float* __restrict__ w1,
    int E1, int nA1, const int* __restrict__ S1, const int* __restrict__ bs1, int nbs1,
    int nblk1, ull* __restrict__ coarse1,
    const int* __restrict__ d2, const int* __restrict__ s2, const float* __restrict__ w2,
    int E2, const int* __restrict__ S2, const int* __restrict__ bs2, int nbs2,
    int nblk2, ull* __restrict__ coarse2) {
  __shared__ int cnt[NB1c];        // hist, then reused as placement cursor
  __shared__ int lscan[NB1c];      // exclusive prefix within block
  __shared__ int cellst[NB1c];     // absolute global cell start
  __shared__ int wtot[16], wbase[16];
  __shared__ int sbs[192];         // scanned chunk bases
  __shared__ ull pay[4096];
  __shared__ unsigned short bkt_of[4096];

  int lb = blockIdx.x;
  const int* dst; const int* src; const float* ew;
  int E, NB, nblk, sh, msk, nbs; const int* S; const int* bs; ull* coarse;
  if (lb < nA1) {
    dst = d1; src = s1; ew = w1; E = E1; NB = NB1c; nblk = nblk1;
    S = S1; bs = bs1; nbs = nbs1; coarse = coarse1; sh = 5; msk = 31;
  } else {
    lb -= nA1;
    dst = d2; src = s2; ew = w2; E = E2; NB = NB2c; nblk = nblk2;
    S = S2; bs = bs2; nbs = nbs2; coarse = coarse2; sh = 4; msk = 15;
  }

  int t = threadIdx.x;
  int lane = t & 63, wv = t >> 6;
  int eb = lb * 4096;
  int ecount = E - eb; if (ecount > 4096) ecount = 4096;

  wave_scan_bsum(bs, nbs, sbs, t);
  for (int i = t; i < NB; i += 1024) cnt[i] = 0;
  __syncthreads();

  // load 4 edges into registers + histogram
  ull pk0 = 0, pk1 = 0, pk2 = 0, pk3 = 0;
  int bk0 = -1, bk1 = -1, bk2 = -1, bk3 = -1;
#define LOADE(R, PK, BK)                                              \
  {                                                                   \
    int e = eb + (R) * 1024 + t;                                      \
    if (e < E) {                                                      \
      int d_ = dst[e];                                                \
      BK = d_ >> sh;                                                  \
      PK = ((ull)__float_as_uint(ew[e]) << 32) |                      \
           (unsigned int)((src[e] << 5) | (d_ & msk));                \
      atomicAdd(&cnt[BK], 1);                                         \
    }                                                                 \
  }
  LOADE(0, pk0, bk0) LOADE(1, pk1, bk1) LOADE(2, pk2, bk2) LOADE(3, pk3, bk3)
#undef LOADE
  __syncthreads();

  // hierarchical scan of cnt -> lscan (thread owns 2 consecutive buckets)
  int i0 = 2 * t, i1 = 2 * t + 1;
  int c0 = (i0 < NB) ? cnt[i0] : 0;
  int c1 = (i1 < NB) ? cnt[i1] : 0;
  int v = c0 + c1;
  int inc = v;
  for (int d_ = 1; d_ < 64; d_ <<= 1) {
    int u = __shfl_up(inc, d_);
    if (lane >= d_) inc += u;
  }
  if (lane == 63) wtot[wv] = inc;
  __syncthreads();
  if (t < 16) {
    int s = 0;
    for (int k = 0; k < t; ++k) s += wtot[k];
    wbase[t] = s;
  }
  __syncthreads();
  int ex = wbase[wv] + inc - v;
  if (i0 < NB) lscan[i0] = ex;
  if (i1 < NB) lscan[i1] = ex + c0;
  __syncthreads();

  // cell starts (absolute) + re-init cnt as placement cursor
  for (int i = t; i < NB; i += 1024) {
    size_t idx = (size_t)i * nblk + lb;
    cellst[i] = S[idx] + sbs[idx >> 12];
    cnt[i] = lscan[i];
  }
  __syncthreads();

  // place payloads bucket-sorted into LDS
#define PLACE(PK, BK)                                                 \
  if (BK >= 0) {                                                      \
    int pos = atomicAdd(&cnt[BK], 1);                                 \
    pay[pos] = PK;                                                    \
    bkt_of[pos] = (unsigned short)(BK);                               \
  }
  PLACE(pk0, bk0) PLACE(pk1, bk1) PLACE(pk2, bk2) PLACE(pk3, bk3)
#undef PLACE
  __syncthreads();

  // write out in sorted order: consecutive lanes -> consecutive addresses
#pragma unroll
  for (int r = 0; r < 4; ++r) {
    int p = r * 1024 + t;
    if (p < ecount) {
      int b_ = bkt_of[p];
      int addr = cellst[b_] + (p - lscan[b_]);
      __builtin_nontemporal_store(pay[p], coarse + addr);
    }
  }
}

// ---------------------------------------------------------------------------
// Fused fine-bin + SpMM block 1: TWO blocks per coarse bucket; each block
// filters & bins its 16-dst half (CAP 1024, ~9.3 KB LDS -> 8 blocks/CU,
// 3126 blocks -> grid saturates). 4 waves x 4 rows.
// ---------------------------------------------------------------------------
__global__ __launch_bounds__(256) void bucket_spmm1_kernel(
    const unsigned int* __restrict__ h_in,   // xb
    const int* __restrict__ S, const int* __restrict__ bs, int nbs, int nblk,
    const ull* __restrict__ coarse, int E,
    unsigned int* __restrict__ h1b) {
  __shared__ ull pay[CAP1H];
  __shared__ int h16[16], c16[16], binofs[16];
  __shared__ int sbs[192];
  int blk = blockIdx.x;
  int b = blk >> 1;         // coarse bucket
  int hb = blk & 1;         // which 16-dst half
  int t = threadIdx.x;
  int wid = t >> 6, lane = t & 63;

  wave_scan_bsum(bs, nbs, sbs, t);
  if (t < 16) { h16[t] = 0; c16[t] = 0; }
  __syncthreads();

  size_t i0 = (size_t)b * nblk;
  int base = S[i0] + sbs[i0 >> 12];
  int end;
  if (b == NB1c - 1) end = E;
  else {
    size_t i1 = (size_t)(b + 1) * nblk;
    end = S[i1] + sbs[i1 >> 12];
  }

  // histogram of OUR half's 16 bins
  for (int i = base + t; i < end; i += 256) {
    int dl5 = (int)(unsigned int)coarse[i] & 31;
    if ((dl5 >> 4) == hb) atomicAdd(&h16[dl5 & 15], 1);
  }
  __syncthreads();
  if (t == 0) {
    int run = 0;
#pragma unroll
    for (int k = 0; k < 16; ++k) { binofs[k] = run; run += h16[k]; }
  }
  __syncthreads();
  int halfcnt = binofs[15] + h16[15];

  if (halfcnt <= CAP1H) {
    for (int i = base + t; i < end; i += 256) {
      ull pk = coarse[i];
      int dl5 = (int)(unsigned int)pk & 31;
      if ((dl5 >> 4) == hb) {
        int rk = atomicAdd(&c16[dl5 & 15], 1);
        pay[binofs[dl5 & 15] + rk] = pk;
      }
    }
    __syncthreads();

#pragma unroll
    for (int r = 0; r < 4; ++r) {
      int dl = wid * 4 + r;                 // bin within half
      int row = b * 32 + hb * 16 + dl;
      if (row >= cN1) break;
      int lo = binofs[dl], hi = lo + h16[dl];
      float accx = 0.f, accy = 0.f, ax1 = 0.f, ay1 = 0.f;
      int j = lo;
      for (; j + 8 <= hi; j += 8) {
        ull p0 = pay[j],     p1 = pay[j + 1], p2 = pay[j + 2], p3 = pay[j + 3];
        ull p4 = pay[j + 4], p5 = pay[j + 5], p6 = pay[j + 6], p7 = pay[j + 7];
        PAY_GATHER(p0, accx, accy) PAY_GATHER(p1, ax1, ay1)
        PAY_GATHER(p2, accx, accy) PAY_GATHER(p3, ax1, ay1)
        PAY_GATHER(p4, accx, accy) PAY_GATHER(p5, ax1, ay1)
        PAY_GATHER(p6, accx, accy) PAY_GATHER(p7, ax1, ay1)
      }
      for (; j < hi; ++j) { ull p0 = pay[j]; PAY_GATHER(p0, accx, accy) }
      h1b[(size_t)row * 64 + lane] = pack_bf2(accx + ax1, accy + ay1);
    }
  } else {
    // slow fallback (statistically unreachable; kept for correctness)
    for (int r = 0; r < 4; ++r) {
      int dl = wid * 4 + r;
      int row = b * 32 + hb * 16 + dl;
      if (row >= cN1) break;
      int want = hb * 16 + dl;
      float accx = 0.f, accy = 0.f;
      for (int i = base; i < end; ++i) {
        ull pk = coarse[i];
        if (((int)(unsigned int)pk & 31) == want) { PAY_GATHER(pk, accx, accy) }
      }
      h1b[(size_t)row * 64 + lane] = pack_bf2(accx, accy);
    }
  }
}

// ---------------------------------------------------------------------------
// Fused fine-bin + SpMM block 2 + linear: one block per coarse bucket of
// graph 2 (16 dst rows, 625 blocks).
// ---------------------------------------------------------------------------
__global__ __launch_bounds__(256) void bucket_spmm2_linear_kernel(
    const unsigned int* __restrict__ h_in,   // h1b
    const int* __restrict__ S, const int* __restrict__ bs, int nbs, int nblk,
    const ull* __restrict__ coarse, int E,
    const float* __restrict__ WT,
    const float* __restrict__ bias,
    float* __restrict__ out) {
  __shared__ ull pay[CAP2];
  __shared__ float hrow[16][DD];
  __shared__ int h16[16], c16[16], binofs[16];
  __shared__ int sbs[64];
  int b = blockIdx.x;
  int t = threadIdx.x;
  int wid = t >> 6, lane = t & 63;

  wave_scan_bsum(bs, nbs, sbs, t);
  if (t < 16) { h16[t] = 0; c16[t] = 0; }
  __syncthreads();

  size_t i0 = (size_t)b * nblk;
  int base = S[i0] + sbs[i0 >> 12];
  int end;
  if (b == NB2c - 1) end = E;
  else {
    size_t i1 = (size_t)(b + 1) * nblk;
    end = S[i1] + sbs[i1 >> 12];
  }
  int count = end - base;

  if (count <= CAP2) {
    for (int i = base + t; i < end; i += 256)
      atomicAdd(&h16[(int)(unsigned int)coarse[i] & 15], 1);
    __syncthreads();
    if (t == 0) {
      int run = 0;
#pragma unroll
      for (int k = 0; k < 16; ++k) { binofs[k] = run; run += h16[k]; }
    }
    __syncthreads();
    for (int i = base + t; i < end; i += 256) {
      ull pk = coarse[i];
      int dl = (int)(unsigned int)pk & 15;
      int rk = atomicAdd(&c16[dl], 1);
      pay[binofs[dl] + rk] = pk;
    }
    __syncthreads();

#pragma unroll
    for (int r = 0; r < 4; ++r) {
      int dl = wid * 4 + r;
      int lo = binofs[dl], hi = lo + h16[dl];
      float accx = 0.f, accy = 0.f, ax1 = 0.f, ay1 = 0.f;
      int j = lo;
      for (; j + 8 <= hi; j += 8) {
        ull p0 = pay[j],     p1 = pay[j + 1], p2 = pay[j + 2], p3 = pay[j + 3];
        ull p4 = pay[j + 4], p5 = pay[j + 5], p6 = pay[j + 6], p7 = pay[j + 7];
        PAY_GATHER(p0, accx, accy) PAY_GATHER(p1, ax1, ay1)
        PAY_GATHER(p2, accx, accy) PAY_GATHER(p3, ax1, ay1)
        PAY_GATHER(p4, accx, accy) PAY_GATHER(p5, ax1, ay1)
        PAY_GATHER(p6, accx, accy) PAY_GATHER(p7, ax1, ay1)
      }
      for (; j < hi; ++j) { ull p0 = pay[j]; PAY_GATHER(p0, accx, accy) }
      float2 hv; hv.x = accx + ax1; hv.y = accy + ay1;
      *reinterpret_cast<float2*>(&hrow[dl][2 * lane]) = hv;
    }
  } else {
    for (int r = 0; r < 4; ++r) {
      int dl = wid * 4 + r;
      float accx = 0.f, accy = 0.f;
      for (int i = base; i < end; ++i) {
        ull pk = coarse[i];
        if (((int)(unsigned int)pk & 15) == dl) { PAY_GATHER(pk, accx, accy) }
      }
      float2 hv; hv.x = accx; hv.y = accy;
      *reinterpret_cast<float2*>(&hrow[dl][2 * lane]) = hv;
    }
  }
  // wave-synchronous: each wave reads only the hrow rows it wrote.

  float2 bb = reinterpret_cast<const float2*>(bias)[lane];
  float a0[4], a1[4];
#pragma unroll
  for (int r = 0; r < 4; ++r) { a0[r] = bb.x; a1[r] = bb.y; }

  const float* hbase = &hrow[wid * 4][0];
#pragma unroll 4
  for (int d = 0; d < DD; ++d) {
    float2 wv = *reinterpret_cast<const float2*>(WT + (size_t)d * DD + 2 * lane);
#pragma unroll
    for (int r = 0; r < 4; ++r) {
      float h = hbase[r * DD + d];   // LDS broadcast
      a0[r] += h * wv.x;
      a1[r] += h * wv.y;
    }
  }
#pragma unroll
  for (int r = 0; r < 4; ++r) {
    int row = b * 16 + wid * 4 + r;
    if (row < cN2) {
      float2 o; o.x = a0[r]; o.y = a1[r];
      reinterpret_cast<float2*>(out + (size_t)row * DD)[lane] = o;
    }
  }
}

static inline size_t align256(size_t x) { return (x + 255) & ~size_t(255); }
static inline int pad16i(int x) { return (x + 15) & ~15; }

extern "C" void kernel_launch(void* const* d_in, const int* in_sizes, int n_in,
                              void* d_out, int out_size, void* d_ws, size_t ws_size,
                              hipStream_t stream) {
  const float* x   = (const float*)d_in[0];
  const float* ew1 = (const float*)d_in[1];
  const float* ew2 = (const float*)d_in[2];
  const float* W   = (const float*)d_in[3];
  const float* b   = (const float*)d_in[4];
  const int* e1_src = (const int*)d_in[5];
  const int* e1_dst = (const int*)d_in[6];
  const int* e2_src = (const int*)d_in[7];
  const int* e2_dst = (const int*)d_in[8];
  float* out = (float*)d_out;

  int E1 = in_sizes[1];
  int E2 = in_sizes[2];

  int nA1 = (E1 + 4095) / 4096;           // 391
  int nA2 = (E2 + 4095) / 4096;           // 79
  int nc1 = pad16i(NB1c * nA1);           // 611136
  int nc2 = pad16i(NB2c * nA2);           // 49376
  int nbs1 = (nc1 + 4095) / 4096;         // 150
  int nbs2 = (nc2 + 4095) / 4096;         // 13

  long long n8 = (long long)cN0 * DD / 8; // 1.6M uint4 outputs
  int ncvt = (int)((n8 + 1023) / 1024);   // 1563 cvt blocks
  int nwt  = (DD * DD + 1023) / 1024;     // 16 wt blocks

  // ---- workspace layout (~59 MB) ----
  char* p = (char*)d_ws;
  unsigned int* xb  = (unsigned int*)p;  p += align256((size_t)cN0 * DD * 2);
  unsigned int* h1b = (unsigned int*)p;  p += align256((size_t)cN1 * DD * 2);
  float* WT = (float*)p;                 p += align256((size_t)DD * DD * 4);
  int* bh1 = (int*)p;                    p += align256((size_t)(nc1 + 16) * 4);
  int* bh2 = (int*)p;                    p += align256((size_t)(nc2 + 16) * 4);
  int* S1  = (int*)p;                    p += align256((size_t)(nc1 + 16) * 4);
  int* S2  = (int*)p;                    p += align256((size_t)(nc2 + 16) * 4);
  int* bsum1 = (int*)p;                  p += align256(4096);
  int* bsum2 = (int*)p;                  p += align256(4096);
  ull* coarse1 = (ull*)p;                p += align256((size_t)E1 * 8);
  ull* coarse2 = (ull*)p;                p += align256((size_t)E2 * 8);

  // 1) prep: passA + x->bf16 + W^T in ONE launch
  prep_kernel<<<nA1 + nA2 + ncvt + nwt, 1024, 0, stream>>>(
      e1_dst, E1, nA1, bh1, e2_dst, E2, nA2, bh2,
      x, xb, n8, ncvt, W, WT);

  // 2) scan -> chunk-local S + RAW chunk sums (consumers scan bsum)
  scan_blk2_kernel<<<nbs1 + nbs2, 256, 0, stream>>>(
      bh1, nc1, S1, bsum1, nbs1, bh2, nc2, S2, bsum2);

  // 3) pass B: LDS-binned, wave-coalesced scatter
  passB_kernel<<<nA1 + nA2, 1024, 0, stream>>>(
      e1_dst, e1_src, ew1, E1, nA1, S1, bsum1, nbs1, nA1, coarse1,
      e2_dst, e2_src, ew2, E2, S2, bsum2, nbs2, nA2, coarse2);

  // 4) fused bin + SpMM block 1: xb -> h1b (2 blocks per bucket)
  bucket_spmm1_kernel<<<2 * NB1c, 256, 0, stream>>>(
      xb, S1, bsum1, nbs1, nA1, coarse1, E1, h1b);

  // 5) fused bin + SpMM block 2 + linear: h1b -> out
  bucket_spmm2_linear_kernel<<<NB2c, 256, 0, stream>>>(
      h1b, S2, bsum2, nbs2, nA2, coarse2, E2, WT, b, out);
}

// Round 15
// 147.970 us; speedup vs baseline: 1.0194x; 1.0194x over previous
//
#include <hip/hip_runtime.h>

#define DD 128

constexpr int cN0 = 100000, cN1 = 50000, cN2 = 10000;
constexpr int NB1c = (cN1 + 31) / 32;   // 1563 buckets of 32 dsts (graph 1)
constexpr int NB2c = (cN2 + 15) / 16;   // 625 buckets of 16 dsts (graph 2)
constexpr int CAP1 = 2048;              // mean 1024, sigma 32 -> safe
constexpr int CAP2 = 1024;              // mean 512,  sigma 23 -> safe

typedef unsigned long long ull;

// ---------------------------------------------------------------------------
// bf16 helpers (packed 2x bf16 in u32; lo 16 = even col, hi 16 = odd col)
// ---------------------------------------------------------------------------
__device__ __forceinline__ float bf_lo(unsigned int u) {
  return __uint_as_float(u << 16);
}
__device__ __forceinline__ float bf_hi(unsigned int u) {
  return __uint_as_float(u & 0xFFFF0000u);
}
__device__ __forceinline__ unsigned int pack_bf2(float a, float b) {
  unsigned int ua = __float_as_uint(a), ub = __float_as_uint(b);
  ua += 0x7FFFu + ((ua >> 16) & 1u);   // round-to-nearest-even
  ub += 0x7FFFu + ((ub >> 16) & 1u);
  return (ua >> 16) | (ub & 0xFFFF0000u);
}

// payload: hi32 = weight bits, lo32 = (src << 5) | dlow
#define PAY_GATHER(PK, VX, VY)                                       \
  {                                                                  \
    int s_ = ((int)(unsigned int)(PK)) >> 5;                         \
    unsigned int v_ = h_in[(size_t)s_ * 64 + lane];                  \
    float w_ = __uint_as_float((unsigned int)((PK) >> 32));          \
    VX += bf_lo(v_) * w_;                                            \
    VY += bf_hi(v_) * w_;                                            \
  }

// ---------------------------------------------------------------------------
// One-wave exclusive scan of raw[0..nb) into lds_out (nb <= 192).
// Caller must __syncthreads() after.
// ---------------------------------------------------------------------------
__device__ __forceinline__ void wave_scan_bsum(
    const int* __restrict__ raw, int nb, int* lds_out, int tid) {
  if (tid < 64) {
    int carry = 0;
    for (int base = 0; base < nb; base += 64) {
      int i = base + tid;
      int orig = (i < nb) ? raw[i] : 0;
      int v = orig;
      for (int d = 1; d < 64; d <<= 1) {
        int u = __shfl_up(v, d);
        if (tid >= d) v += u;
      }
      if (i < nb) lds_out[i] = carry + v - orig;
      carry += __shfl(v, 63);
    }
  }
}

// ---------------------------------------------------------------------------
// Prep kernel (one launch): blocks [0, nA) run pass A (coarse histogram),
// blocks [nA, nA+ncvt) convert x -> bf16, last 16 blocks transpose W.
// ---------------------------------------------------------------------------
__global__ __launch_bounds__(1024) void prep_kernel(
    const int* __restrict__ d1, int E1, int nA1, int* __restrict__ bh1,
    const int* __restrict__ d2, int E2, int nA2, int* __restrict__ bh2,
    const float* __restrict__ x, unsigned int* __restrict__ xb, long long n8,
    int ncvt, const float* __restrict__ W, float* __restrict__ WT) {
  __shared__ int hist[NB1c];
  int blk = blockIdx.x;
  int t = threadIdx.x;
  int nA = nA1 + nA2;

  if (blk < nA) {
    const int* dst; int E, NB, nblk, sh; int* bh; int lb;
    if (blk < nA1) { dst = d1; E = E1; NB = NB1c; nblk = nA1; bh = bh1; sh = 5; lb = blk; }
    else { dst = d2; E = E2; NB = NB2c; nblk = nA2; bh = bh2; sh = 4; lb = blk - nA1; }

    for (int i = t; i < NB; i += 1024) hist[i] = 0;
    __syncthreads();

    int eb = lb * 4096;
#pragma unroll
    for (int r = 0; r < 4; ++r) {
      int e = eb + r * 1024 + t;
      if (e < E) atomicAdd(&hist[dst[e] >> sh], 1);
    }
    __syncthreads();
    for (int i = t; i < NB; i += 1024) bh[(size_t)i * nblk + lb] = hist[i];
  } else if (blk < nA + ncvt) {
    long long i = (long long)(blk - nA) * 1024 + t;
    if (i < n8) {
      const float4* f4 = reinterpret_cast<const float4*>(x) + i * 2;
      float4 a = f4[0];
      float4 b = f4[1];
      uint4 o;
      o.x = pack_bf2(a.x, a.y);
      o.y = pack_bf2(a.z, a.w);
      o.z = pack_bf2(b.x, b.y);
      o.w = pack_bf2(b.z, b.w);
      reinterpret_cast<uint4*>(xb)[i] = o;
    }
  } else {
    int idx = (blk - nA - ncvt) * 1024 + t;
    if (idx < DD * DD) {
      int c = idx >> 7;
      int d = idx & 127;
      WT[d * DD + c] = W[idx];
    }
  }
}

// ---------------------------------------------------------------------------
// Scan stage 1: per-4096-chunk exclusive scan (256 thr x 16 via int4).
// S stays CHUNK-LOCAL; bsum holds RAW chunk totals (consumers scan them).
// ---------------------------------------------------------------------------
__global__ __launch_bounds__(256) void scan_blk2_kernel(
    const int* __restrict__ cnt1, int n1, int* __restrict__ ofs1, int* __restrict__ bsum1, int nb1,
    const int* __restrict__ cnt2, int n2, int* __restrict__ ofs2, int* __restrict__ bsum2) {
  const int* cnt; int n; int* ofs; int* bsum; int lb;
  if ((int)blockIdx.x < nb1) { cnt = cnt1; n = n1; ofs = ofs1; bsum = bsum1; lb = blockIdx.x; }
  else                       { cnt = cnt2; n = n2; ofs = ofs2; bsum = bsum2; lb = blockIdx.x - nb1; }

  __shared__ int tsum[256];
  int t = threadIdx.x;
  int base = lb * 4096 + t * 16;
  bool in = (base + 16 <= n);

  int v[16];
  if (in) {
    const int4* p4 = reinterpret_cast<const int4*>(cnt + base);
    int4 a = p4[0], b = p4[1], c = p4[2], d = p4[3];
    v[0]=a.x; v[1]=a.y; v[2]=a.z; v[3]=a.w;
    v[4]=b.x; v[5]=b.y; v[6]=b.z; v[7]=b.w;
    v[8]=c.x; v[9]=c.y; v[10]=c.z; v[11]=c.w;
    v[12]=d.x; v[13]=d.y; v[14]=d.z; v[15]=d.w;
  } else {
#pragma unroll
    for (int k = 0; k < 16; ++k) v[k] = 0;
  }
#pragma unroll
  for (int k = 1; k < 16; ++k) v[k] += v[k - 1];

  tsum[t] = v[15];
  __syncthreads();
  for (int d_ = 1; d_ < 256; d_ <<= 1) {
    int x = (t >= d_) ? tsum[t - d_] : 0;
    __syncthreads();
    tsum[t] += x;
    __syncthreads();
  }
  int ex = (t == 0) ? 0 : tsum[t - 1];

  if (in) {
    int4* q = reinterpret_cast<int4*>(ofs + base);
    q[0] = make_int4(ex,         ex + v[0],  ex + v[1],  ex + v[2]);
    q[1] = make_int4(ex + v[3],  ex + v[4],  ex + v[5],  ex + v[6]);
    q[2] = make_int4(ex + v[7],  ex + v[8],  ex + v[9],  ex + v[10]);
    q[3] = make_int4(ex + v[11], ex + v[12], ex + v[13], ex + v[14]);
  }
  if (t == 255) bsum[lb] = tsum[255];
}

// ---------------------------------------------------------------------------
// Pass B (LDS-binned, wave-coalesced scatter). Hierarchical wave-shuffle
// scan (2 barriers).
// ---------------------------------------------------------------------------
__global__ __launch_bounds__(1024) void passB_kernel(
    const int* __restrict__ d1, const int* __restrict__ s1, const float* __restrict__ w1,
    int E1, int nA1, const int* __restrict__ S1, const int* __restrict__ bs1, int nbs1,
    int nblk1, ull* __restrict__ coarse1,
    const int* __restrict__ d2, const int* __restrict__ s2, const float* __restrict__ w2,
    int E2, const int* __restrict__ S2, const int* __restrict__ bs2, int nbs2,
    int nblk2, ull* __restrict__ coarse2) {
  __shared__ int cnt[NB1c];        // hist, then reused as placement cursor
  __shared__ int lscan[NB1c];      // exclusive prefix within block
  __shared__ int cellst[NB1c];     // absolute global cell start
  __shared__ int wtot[16], wbase[16];
  __shared__ int sbs[192];         // scanned chunk bases
  __shared__ ull pay[4096];
  __shared__ unsigned short bkt_of[4096];

  int lb = blockIdx.x;
  const int* dst; const int* src; const float* ew;
  int E, NB, nblk, sh, msk, nbs; const int* S; const int* bs; ull* coarse;
  if (lb < nA1) {
    dst = d1; src = s1; ew = w1; E = E1; NB = NB1c; nblk = nblk1;
    S = S1; bs = bs1; nbs = nbs1; coarse = coarse1; sh = 5; msk = 31;
  } else {
    lb -= nA1;
    dst = d2; src = s2; ew = w2; E = E2; NB = NB2c; nblk = nblk2;
    S = S2; bs = bs2; nbs = nbs2; coarse = coarse2; sh = 4; msk = 15;
  }

  int t = threadIdx.x;
  int lane = t & 63, wv = t >> 6;
  int eb = lb * 4096;
  int ecount = E - eb; if (ecount > 4096) ecount = 4096;

  wave_scan_bsum(bs, nbs, sbs, t);
  for (int i = t; i < NB; i += 1024) cnt[i] = 0;
  __syncthreads();

  // load 4 edges into registers + histogram
  ull pk0 = 0, pk1 = 0, pk2 = 0, pk3 = 0;
  int bk0 = -1, bk1 = -1, bk2 = -1, bk3 = -1;
#define LOADE(R, PK, BK)                                              \
  {                                                                   \
    int e = eb + (R) * 1024 + t;                                      \
    if (e < E) {                                                      \
      int d_ = dst[e];                                                \
      BK = d_ >> sh;                                                  \
      PK = ((ull)__float_as_uint(ew[e]) << 32) |                      \
           (unsigned int)((src[e] << 5) | (d_ & msk));                \
      atomicAdd(&cnt[BK], 1);                                         \
    }                                                                 \
  }
  LOADE(0, pk0, bk0) LOADE(1, pk1, bk1) LOADE(2, pk2, bk2) LOADE(3, pk3, bk3)
#undef LOADE
  __syncthreads();

  // hierarchical scan of cnt -> lscan (thread owns 2 consecutive buckets)
  int i0 = 2 * t, i1 = 2 * t + 1;
  int c0 = (i0 < NB) ? cnt[i0] : 0;
  int c1 = (i1 < NB) ? cnt[i1] : 0;
  int v = c0 + c1;
  int inc = v;
  for (int d_ = 1; d_ < 64; d_ <<= 1) {
    int u = __shfl_up(inc, d_);
    if (lane >= d_) inc += u;
  }
  if (lane == 63) wtot[wv] = inc;
  __syncthreads();
  if (t < 16) {
    int s = 0;
    for (int k = 0; k < t; ++k) s += wtot[k];
    wbase[t] = s;
  }
  __syncthreads();
  int ex = wbase[wv] + inc - v;
  if (i0 < NB) lscan[i0] = ex;
  if (i1 < NB) lscan[i1] = ex + c0;
  __syncthreads();

  // cell starts (absolute) + re-init cnt as placement cursor
  for (int i = t; i < NB; i += 1024) {
    size_t idx = (size_t)i * nblk + lb;
    cellst[i] = S[idx] + sbs[idx >> 12];
    cnt[i] = lscan[i];
  }
  __syncthreads();

  // place payloads bucket-sorted into LDS
#define PLACE(PK, BK)                                                 \
  if (BK >= 0) {                                                      \
    int pos = atomicAdd(&cnt[BK], 1);                                 \
    pay[pos] = PK;                                                    \
    bkt_of[pos] = (unsigned short)(BK);                               \
  }
  PLACE(pk0, bk0) PLACE(pk1, bk1) PLACE(pk2, bk2) PLACE(pk3, bk3)
#undef PLACE
  __syncthreads();

  // write out in sorted order: consecutive lanes -> consecutive addresses
#pragma unroll
  for (int r = 0; r < 4; ++r) {
    int p = r * 1024 + t;
    if (p < ecount) {
      int b_ = bkt_of[p];
      int addr = cellst[b_] + (p - lscan[b_]);
      __builtin_nontemporal_store(pay[p], coarse + addr);
    }
  }
}

// ---------------------------------------------------------------------------
// Fused fine-bin + SpMM block 1: one block per coarse bucket (32 dst rows).
// CAP1=2048 (~17 KB LDS -> 8 blocks/CU). Unroll-8 gather.
// ---------------------------------------------------------------------------
__global__ __launch_bounds__(256) void bucket_spmm1_kernel(
    const unsigned int* __restrict__ h_in,   // xb
    const int* __restrict__ S, const int* __restrict__ bs, int nbs, int nblk,
    const ull* __restrict__ coarse, int E,
    unsigned int* __restrict__ h1b) {
  __shared__ ull pay[CAP1];
  __shared__ int h32[32], c32[32], binofs[32];
  __shared__ int sbs[192];
  int b = blockIdx.x;
  int t = threadIdx.x;
  int wid = t >> 6, lane = t & 63;

  wave_scan_bsum(bs, nbs, sbs, t);
  if (t < 32) { h32[t] = 0; c32[t] = 0; }
  __syncthreads();

  size_t i0 = (size_t)b * nblk;
  int base = S[i0] + sbs[i0 >> 12];
  int end;
  if (b == NB1c - 1) end = E;
  else {
    size_t i1 = (size_t)(b + 1) * nblk;
    end = S[i1] + sbs[i1 >> 12];
  }
  int count = end - base;

  if (count <= CAP1) {
    for (int i = base + t; i < end; i += 256)
      atomicAdd(&h32[(int)(unsigned int)coarse[i] & 31], 1);
    __syncthreads();
    if (t == 0) {
      int run = 0;
#pragma unroll
      for (int k = 0; k < 32; ++k) { binofs[k] = run; run += h32[k]; }
    }
    __syncthreads();
    for (int i = base + t; i < end; i += 256) {
      ull pk = coarse[i];
      int dl = (int)(unsigned int)pk & 31;
      int rk = atomicAdd(&c32[dl], 1);
      pay[binofs[dl] + rk] = pk;
    }
    __syncthreads();

#pragma unroll
    for (int r = 0; r < 8; ++r) {
      int dl = wid * 8 + r;
      int row = b * 32 + dl;
      if (row >= cN1) break;
      int lo = binofs[dl], hi = lo + h32[dl];
      float accx = 0.f, accy = 0.f, ax1 = 0.f, ay1 = 0.f;
      int j = lo;
      for (; j + 8 <= hi; j += 8) {
        ull p0 = pay[j],     p1 = pay[j + 1], p2 = pay[j + 2], p3 = pay[j + 3];
        ull p4 = pay[j + 4], p5 = pay[j + 5], p6 = pay[j + 6], p7 = pay[j + 7];
        PAY_GATHER(p0, accx, accy) PAY_GATHER(p1, ax1, ay1)
        PAY_GATHER(p2, accx, accy) PAY_GATHER(p3, ax1, ay1)
        PAY_GATHER(p4, accx, accy) PAY_GATHER(p5, ax1, ay1)
        PAY_GATHER(p6, accx, accy) PAY_GATHER(p7, ax1, ay1)
      }
      for (; j < hi; ++j) { ull p0 = pay[j]; PAY_GATHER(p0, accx, accy) }
      h1b[(size_t)row * 64 + lane] = pack_bf2(accx + ax1, accy + ay1);
    }
  } else {
    // slow fallback (statistically unreachable; kept for correctness)
    for (int r = 0; r < 8; ++r) {
      int dl = wid * 8 + r;
      int row = b * 32 + dl;
      if (row >= cN1) break;
      float accx = 0.f, accy = 0.f;
      for (int i = base; i < end; ++i) {
        ull pk = coarse[i];
        if (((int)(unsigned int)pk & 31) == dl) { PAY_GATHER(pk, accx, accy) }
      }
      h1b[(size_t)row * 64 + lane] = pack_bf2(accx, accy);
    }
  }
}

// ---------------------------------------------------------------------------
// Fused fine-bin + SpMM block 2 + linear: one block per coarse bucket of
// graph 2 (16 dst rows, 625 blocks).
// ---------------------------------------------------------------------------
__global__ __launch_bounds__(256) void bucket_spmm2_linear_kernel(
    const unsigned int* __restrict__ h_in,   // h1b
    const int* __restrict__ S, const int* __restrict__ bs, int nbs, int nblk,
    const ull* __restrict__ coarse, int E,
    const float* __restrict__ WT,
    const float* __restrict__ bias,
    float* __restrict__ out) {
  __shared__ ull pay[CAP2];
  __shared__ float hrow[16][DD];
  __shared__ int h16[16], c16[16], binofs[16];
  __shared__ int sbs[64];
  int b = blockIdx.x;
  int t = threadIdx.x;
  int wid = t >> 6, lane = t & 63;

  wave_scan_bsum(bs, nbs, sbs, t);
  if (t < 16) { h16[t] = 0; c16[t] = 0; }
  __syncthreads();

  size_t i0 = (size_t)b * nblk;
  int base = S[i0] + sbs[i0 >> 12];
  int end;
  if (b == NB2c - 1) end = E;
  else {
    size_t i1 = (size_t)(b + 1) * nblk;
    end = S[i1] + sbs[i1 >> 12];
  }
  int count = end - base;

  if (count <= CAP2) {
    for (int i = base + t; i < end; i += 256)
      atomicAdd(&h16[(int)(unsigned int)coarse[i] & 15], 1);
    __syncthreads();
    if (t == 0) {
      int run = 0;
#pragma unroll
      for (int k = 0; k < 16; ++k) { binofs[k] = run; run += h16[k]; }
    }
    __syncthreads();
    for (int i = base + t; i < end; i += 256) {
      ull pk = coarse[i];
      int dl = (int)(unsigned int)pk & 15;
      int rk = atomicAdd(&c16[dl], 1);
      pay[binofs[dl] + rk] = pk;
    }
    __syncthreads();

#pragma unroll
    for (int r = 0; r < 4; ++r) {
      int dl = wid * 4 + r;
      int lo = binofs[dl], hi = lo + h16[dl];
      float accx = 0.f, accy = 0.f, ax1 = 0.f, ay1 = 0.f;
      int j = lo;
      for (; j + 8 <= hi; j += 8) {
        ull p0 = pay[j],     p1 = pay[j + 1], p2 = pay[j + 2], p3 = pay[j + 3];
        ull p4 = pay[j + 4], p5 = pay[j + 5], p6 = pay[j + 6], p7 = pay[j + 7];
        PAY_GATHER(p0, accx, accy) PAY_GATHER(p1, ax1, ay1)
        PAY_GATHER(p2, accx, accy) PAY_GATHER(p3, ax1, ay1)
        PAY_GATHER(p4, accx, accy) PAY_GATHER(p5, ax1, ay1)
        PAY_GATHER(p6, accx, accy) PAY_GATHER(p7, ax1, ay1)
      }
      for (; j < hi; ++j) { ull p0 = pay[j]; PAY_GATHER(p0, accx, accy) }
      float2 hv; hv.x = accx + ax1; hv.y = accy + ay1;
      *reinterpret_cast<float2*>(&hrow[dl][2 * lane]) = hv;
    }
  } else {
    for (int r = 0; r < 4; ++r) {
      int dl = wid * 4 + r;
      float accx = 0.f, accy = 0.f;
      for (int i = base; i < end; ++i) {
        ull pk = coarse[i];
        if (((int)(unsigned int)pk & 15) == dl) { PAY_GATHER(pk, accx, accy) }
      }
      float2 hv; hv.x = accx; hv.y = accy;
      *reinterpret_cast<float2*>(&hrow[dl][2 * lane]) = hv;
    }
  }
  // wave-synchronous: each wave reads only the hrow rows it wrote.

  float2 bb = reinterpret_cast<const float2*>(bias)[lane];
  float a0[4], a1[4];
#pragma unroll
  for (int r = 0; r < 4; ++r) { a0[r] = bb.x; a1[r] = bb.y; }

  const float* hbase = &hrow[wid * 4][0];
#pragma unroll 4
  for (int d = 0; d < DD; ++d) {
    float2 wv = *reinterpret_cast<const float2*>(WT + (size_t)d * DD + 2 * lane);
#pragma unroll
    for (int r = 0; r < 4; ++r) {
      float h = hbase[r * DD + d];   // LDS broadcast
      a0[r] += h * wv.x;
      a1[r] += h * wv.y;
    }
  }
#pragma unroll
  for (int r = 0; r < 4; ++r) {
    int row = b * 16 + wid * 4 + r;
    if (row < cN2) {
      float2 o; o.x = a0[r]; o.y = a1[r];
      reinterpret_cast<float2*>(out + (size_t)row * DD)[lane] = o;
    }
  }
}

static inline size_t align256(size_t x) { return (x + 255) & ~size_t(255); }
static inline int pad16i(int x) { return (x + 15) & ~15; }

extern "C" void kernel_launch(void* const* d_in, const int* in_sizes, int n_in,
                              void* d_out, int out_size, void* d_ws, size_t ws_size,
                              hipStream_t stream) {
  const float* x   = (const float*)d_in[0];
  const float* ew1 = (const float*)d_in[1];
  const float* ew2 = (const float*)d_in[2];
  const float* W   = (const float*)d_in[3];
  const float* b   = (const float*)d_in[4];
  const int* e1_src = (const int*)d_in[5];
  const int* e1_dst = (const int*)d_in[6];
  const int* e2_src = (const int*)d_in[7];
  const int* e2_dst = (const int*)d_in[8];
  float* out = (float*)d_out;

  int E1 = in_sizes[1];
  int E2 = in_sizes[2];

  int nA1 = (E1 + 4095) / 4096;           // 391
  int nA2 = (E2 + 4095) / 4096;           // 79
  int nc1 = pad16i(NB1c * nA1);           // 611136
  int nc2 = pad16i(NB2c * nA2);           // 49376
  int nbs1 = (nc1 + 4095) / 4096;         // 150
  int nbs2 = (nc2 + 4095) / 4096;         // 13

  long long n8 = (long long)cN0 * DD / 8; // 1.6M uint4 outputs
  int ncvt = (int)((n8 + 1023) / 1024);   // 1563 cvt blocks
  int nwt  = (DD * DD + 1023) / 1024;     // 16 wt blocks

  // ---- workspace layout (~59 MB) ----
  char* p = (char*)d_ws;
  unsigned int* xb  = (unsigned int*)p;  p += align256((size_t)cN0 * DD * 2);
  unsigned int* h1b = (unsigned int*)p;  p += align256((size_t)cN1 * DD * 2);
  float* WT = (float*)p;                 p += align256((size_t)DD * DD * 4);
  int* bh1 = (int*)p;                    p += align256((size_t)(nc1 + 16) * 4);
  int* bh2 = (int*)p;                    p += align256((size_t)(nc2 + 16) * 4);
  int* S1  = (int*)p;                    p += align256((size_t)(nc1 + 16) * 4);
  int* S2  = (int*)p;                    p += align256((size_t)(nc2 + 16) * 4);
  int* bsum1 = (int*)p;                  p += align256(4096);
  int* bsum2 = (int*)p;                  p += align256(4096);
  ull* coarse1 = (ull*)p;                p += align256((size_t)E1 * 8);
  ull* coarse2 = (ull*)p;                p += align256((size_t)E2 * 8);

  // 1) prep: passA + x->bf16 + W^T in ONE launch
  prep_kernel<<<nA1 + nA2 + ncvt + nwt, 1024, 0, stream>>>(
      e1_dst, E1, nA1, bh1, e2_dst, E2, nA2, bh2,
      x, xb, n8, ncvt, W, WT);

  // 2) scan -> chunk-local S + RAW chunk sums (consumers scan bsum)
  scan_blk2_kernel<<<nbs1 + nbs2, 256, 0, stream>>>(
      bh1, nc1, S1, bsum1, nbs1, bh2, nc2, S2, bsum2);

  // 3) pass B: LDS-binned, wave-coalesced scatter
  passB_kernel<<<nA1 + nA2, 1024, 0, stream>>>(
      e1_dst, e1_src, ew1, E1, nA1, S1, bsum1, nbs1, nA1, coarse1,
      e2_dst, e2_src, ew2, E2, S2, bsum2, nbs2, nA2, coarse2);

  // 4) fused bin + SpMM block 1: xb -> h1b (one block per bucket)
  bucket_spmm1_kernel<<<NB1c, 256, 0, stream>>>(
      xb, S1, bsum1, nbs1, nA1, coarse1, E1, h1b);

  // 5) fused bin + SpMM block 2 + linear: h1b -> out
  bucket_spmm2_linear_kernel<<<NB2c, 256, 0, stream>>>(
      h1b, S2, bsum2, nbs2, nA2, coarse2, E2, WT, b, out);
}